// Round 1
// baseline (301.718 us; speedup 1.0000x reference)
//
#include <hip/hip_runtime.h>
#include <hip/hip_bf16.h>

// Problem constants
#define BQ 8      // batches
#define NN 2048   // train rows (keys)
#define MM 1024   // test rows (queries)
#define EE 512    // input size
#define NH 6      // heads
#define AA 384    // attn size (NH*64)
#define CC 512    // classes

typedef __bf16 bf16x8 __attribute__((ext_vector_type(8)));
typedef float  f32x4  __attribute__((ext_vector_type(4)));
using bf16 = __hip_bfloat16;

static __device__ __forceinline__ f32x4 mfma16(bf16x8 a, bf16x8 b, f32x4 c) {
  return __builtin_amdgcn_mfma_f32_16x16x32_bf16(a, b, c, 0, 0, 0);
}

static __device__ __forceinline__ unsigned short f2bf(float x) {
  union { __hip_bfloat16 h; unsigned short u; } v;
  v.h = __float2bfloat16(x);
  return v.u;
}

// ---------------- f32 -> bf16 vectorized convert ----------------
__global__ void cvt_kernel(const float4* __restrict__ in, ushort4* __restrict__ out, int n4) {
  int stride = gridDim.x * blockDim.x;
  for (int i = blockIdx.x * blockDim.x + threadIdx.x; i < n4; i += stride) {
    float4 v = in[i];
    ushort4 o;
    o.x = f2bf(v.x); o.y = f2bf(v.y); o.z = f2bf(v.z); o.w = f2bf(v.w);
    out[i] = o;
  }
}

// ---------------- W[K][N] -> WT[N][K] bf16 ----------------
__global__ void transw_kernel(const float* __restrict__ W, bf16* __restrict__ WT) {
  int i = blockIdx.x * blockDim.x + threadIdx.x;
  if (i < EE * AA) {
    int k = i / AA, n = i - k * AA;
    WT[n * EE + k] = __float2bfloat16(W[i]);
  }
}

// ---------------- projections: C[m][384] = A[m][512] @ WT^T + bias, (*scale) ----------------
// block = 4 waves, each wave does 16 m-rows over all 24 n-tiles. Frags direct from global.
__global__ __launch_bounds__(256) void proj_kernel(
    const bf16* __restrict__ testB, const bf16* __restrict__ trainB,
    const bf16* __restrict__ WqT, const bf16* __restrict__ WkT,
    const float* __restrict__ bq, const float* __restrict__ bk,
    bf16* __restrict__ Qb, bf16* __restrict__ Kb)
{
  int bid = blockIdx.x;
  const bf16* A; const bf16* WT; const float* bias; bf16* C; float scale; int m0;
  if (bid < (BQ * MM / 64)) {           // 128 Q blocks
    A = testB; WT = WqT; bias = bq; C = Qb; scale = 0.125f; m0 = bid * 64;
  } else {                               // 256 K blocks
    int k = bid - (BQ * MM / 64);
    A = trainB; WT = WkT; bias = bk; C = Kb; scale = 1.0f; m0 = k * 64;
  }
  int tid = threadIdx.x, wid = tid >> 6, lane = tid & 63;
  m0 += wid * 16;
  int row = lane & 15, hi = lane >> 4;

  bf16x8 af[16];
  const bf16* arow = A + (size_t)(m0 + row) * EE + hi * 8;
  #pragma unroll
  for (int ks = 0; ks < 16; ks++) af[ks] = *reinterpret_cast<const bf16x8*>(arow + ks * 32);

  #pragma unroll 1
  for (int nt = 0; nt < 24; nt++) {
    const bf16* wrow = WT + (size_t)(nt * 16 + row) * EE + hi * 8;
    f32x4 acc0 = {0.f, 0.f, 0.f, 0.f}, acc1 = {0.f, 0.f, 0.f, 0.f};
    #pragma unroll
    for (int ks = 0; ks < 16; ks += 2) {
      acc0 = mfma16(af[ks],     *reinterpret_cast<const bf16x8*>(wrow + ks * 32), acc0);
      acc1 = mfma16(af[ks + 1], *reinterpret_cast<const bf16x8*>(wrow + (ks + 1) * 32), acc1);
    }
    f32x4 acc = acc0 + acc1;
    int ocol = nt * 16 + row;           // D: col = lane&15
    float bv = bias[ocol];
    #pragma unroll
    for (int j = 0; j < 4; j++) {       // D: row = (lane>>4)*4 + j
      int orow = m0 + hi * 4 + j;
      C[(size_t)orow * AA + ocol] = __float2bfloat16((acc[j] + bv) * scale);
    }
  }
}

// ---------------- pass 1: Z partials. grid = 8b * 16mt(64) * 4nc(512) ----------------
__global__ __launch_bounds__(256) void zpass_kernel(
    const bf16* __restrict__ Qb, const bf16* __restrict__ Kb, float* __restrict__ Zp)
{
  int id = blockIdx.x;
  int b = id & 7; int r = id >> 3; int mt = r & 15; int nc = r >> 4;
  int tid = threadIdx.x, wid = tid >> 6, lane = tid & 63;
  int m0 = mt * 64 + wid * 16, n0 = nc * 512;
  int row = lane & 15, hi = lane >> 4;

  bf16x8 qf[12];
  const bf16* qrow = Qb + ((size_t)(b * MM + m0 + row)) * AA + hi * 8;
  #pragma unroll
  for (int ks = 0; ks < 12; ks++) qf[ks] = *reinterpret_cast<const bf16x8*>(qrow + ks * 32);

  float zacc[NH][4];
  #pragma unroll
  for (int h = 0; h < NH; h++)
    #pragma unroll
    for (int j = 0; j < 4; j++) zacc[h][j] = 0.f;

  const bf16* kbase = Kb + ((size_t)(b * NN + n0 + row)) * AA + hi * 8;
  #pragma unroll 1
  for (int nt = 0; nt < 32; nt++) {
    const bf16* krow = kbase + (size_t)nt * 16 * AA;
    bf16x8 kf[12];
    #pragma unroll
    for (int ks = 0; ks < 12; ks++) kf[ks] = *reinterpret_cast<const bf16x8*>(krow + ks * 32);
    #pragma unroll
    for (int h = 0; h < NH; h++) {
      f32x4 acc = {0.f, 0.f, 0.f, 0.f};
      acc = mfma16(qf[2 * h], kf[2 * h], acc);
      acc = mfma16(qf[2 * h + 1], kf[2 * h + 1], acc);
      #pragma unroll
      for (int j = 0; j < 4; j++) zacc[h][j] += __expf(acc[j]);
    }
  }
  // reduce over the 16 columns (low 4 lane bits)
  #pragma unroll
  for (int h = 0; h < NH; h++)
    #pragma unroll
    for (int j = 0; j < 4; j++) {
      float v = zacc[h][j];
      v += __shfl_xor(v, 1); v += __shfl_xor(v, 2);
      v += __shfl_xor(v, 4); v += __shfl_xor(v, 8);
      zacc[h][j] = v;
    }
  if (row == 0) {
    #pragma unroll
    for (int h = 0; h < NH; h++)
      #pragma unroll
      for (int j = 0; j < 4; j++)
        Zp[(((size_t)nc * 8 + b) * NH + h) * MM + m0 + hi * 4 + j] = zacc[h][j];
  }
}

// ---------------- pass 2: recompute scores, normalize, scatter, log ----------------
// grid = 256 (8b * 32mt(32)), 512 threads (8 waves: 2 m-halves x 4 n-quarters)
__global__ __launch_bounds__(512) void scatter_kernel(
    const bf16* __restrict__ Qb, const bf16* __restrict__ Kb,
    const int* __restrict__ targets, const float* __restrict__ Zp,
    float* __restrict__ out)
{
  __shared__ float sbins[32 * 512];   // exactly 64 KB, XOR-swizzled columns
  int id = blockIdx.x;
  int b = id & 7; int mt = id >> 3;
  int tid = threadIdx.x, wid = tid >> 6, lane = tid & 63;
  int wm = wid & 1, wn = wid >> 1;
  int m0 = mt * 32 + wm * 16, n0 = wn * 512;
  int row = lane & 15, hi = lane >> 4;

  for (int i = tid; i < 32 * 512; i += 512) sbins[i] = 0.f;
  __syncthreads();

  bf16x8 qf[12];
  const bf16* qrow = Qb + ((size_t)(b * MM + m0 + row)) * AA + hi * 8;
  #pragma unroll
  for (int ks = 0; ks < 12; ks++) qf[ks] = *reinterpret_cast<const bf16x8*>(qrow + ks * 32);

  float rz[NH][4];
  #pragma unroll
  for (int h = 0; h < NH; h++)
    #pragma unroll
    for (int j = 0; j < 4; j++) {
      int m = m0 + hi * 4 + j;
      float z = 0.f;
      #pragma unroll
      for (int p = 0; p < 4; p++) z += Zp[(((size_t)p * 8 + b) * NH + h) * MM + m];
      rz[h][j] = 1.0f / z;
    }

  const int* tgt = targets + b * NN;
  const bf16* kbase = Kb + ((size_t)(b * NN + n0 + row)) * AA + hi * 8;
  #pragma unroll 1
  for (int nt = 0; nt < 32; nt++) {
    const bf16* krow = kbase + (size_t)nt * 16 * AA;
    bf16x8 kf[12];
    #pragma unroll
    for (int ks = 0; ks < 12; ks++) kf[ks] = *reinterpret_cast<const bf16x8*>(krow + ks * 32);
    float s0 = 0.f, s1 = 0.f, s2 = 0.f, s3 = 0.f;
    #pragma unroll
    for (int h = 0; h < NH; h++) {
      f32x4 acc = {0.f, 0.f, 0.f, 0.f};
      acc = mfma16(qf[2 * h], kf[2 * h], acc);
      acc = mfma16(qf[2 * h + 1], kf[2 * h + 1], acc);
      s0 += __expf(acc[0]) * rz[h][0];
      s1 += __expf(acc[1]) * rz[h][1];
      s2 += __expf(acc[2]) * rz[h][2];
      s3 += __expf(acc[3]) * rz[h][3];
    }
    int c = tgt[n0 + nt * 16 + row];   // D col = lane&15 -> this lane's n
    int r0 = wm * 16 + hi * 4;
    // XOR column swizzle breaks the 4-lanes-same-class same-bank conflict
    atomicAdd(&sbins[(r0 + 0) * 512 + (c ^ ((r0 + 0) & 31))], s0);
    atomicAdd(&sbins[(r0 + 1) * 512 + (c ^ ((r0 + 1) & 31))], s1);
    atomicAdd(&sbins[(r0 + 2) * 512 + (c ^ ((r0 + 2) & 31))], s2);
    atomicAdd(&sbins[(r0 + 3) * 512 + (c ^ ((r0 + 3) & 31))], s3);
  }
  __syncthreads();

  const float inv6 = 1.0f / 6.0f;
  for (int i = tid; i < 32 * 512; i += 512) {
    int mi = i >> 9, c = i & 511;
    float v = sbins[mi * 512 + (c ^ (mi & 31))] * inv6;
    out[((size_t)(mt * 32 + mi) * BQ + b) * CC + c] = __logf(fmaxf(v, 1e-5f) + 3e-5f);
  }
}

extern "C" void kernel_launch(void* const* d_in, const int* in_sizes, int n_in,
                              void* d_out, int out_size, void* d_ws, size_t ws_size,
                              hipStream_t stream) {
  const float* train = (const float*)d_in[0];
  const float* test  = (const float*)d_in[1];
  const int*   tgt   = (const int*)d_in[2];
  const float* Wq    = (const float*)d_in[3];
  const float* bq    = (const float*)d_in[4];
  const float* Wk    = (const float*)d_in[5];
  const float* bk    = (const float*)d_in[6];
  float* out = (float*)d_out;

  char* ws = (char*)d_ws;
  bf16*  trainB = (bf16*)(ws);                    // 16,777,216 B
  bf16*  testB  = (bf16*)(ws + 16777216);         //  8,388,608 B
  bf16*  WqT    = (bf16*)(ws + 25165824);         //    393,216 B
  bf16*  WkT    = (bf16*)(ws + 25559040);         //    393,216 B
  bf16*  Qb     = (bf16*)(ws + 25952256);         //  6,291,456 B
  bf16*  Kb     = (bf16*)(ws + 32243712);         // 12,582,912 B
  float* Zp     = (float*)(ws + 44826624);        //    786,432 B  (total ~45.6 MB)

  cvt_kernel<<<1024, 256, 0, stream>>>((const float4*)train, (ushort4*)trainB, BQ * NN * EE / 4);
  cvt_kernel<<<1024, 256, 0, stream>>>((const float4*)test,  (ushort4*)testB,  BQ * MM * EE / 4);
  transw_kernel<<<(EE * AA + 255) / 256, 256, 0, stream>>>(Wq, WqT);
  transw_kernel<<<(EE * AA + 255) / 256, 256, 0, stream>>>(Wk, WkT);
  proj_kernel<<<384, 256, 0, stream>>>(testB, trainB, WqT, WkT, bq, bk, Qb, Kb);
  zpass_kernel<<<512, 256, 0, stream>>>(Qb, Kb, Zp);
  scatter_kernel<<<256, 512, 0, stream>>>(Qb, Kb, tgt, Zp, out);
}